// Round 1
// baseline (506.698 us; speedup 1.0000x reference)
//
#include <hip/hip_runtime.h>
#include <hip/hip_bf16.h>
#include <stdint.h>

typedef unsigned short u16;
typedef __bf16 bf16_8 __attribute__((ext_vector_type(8)));
typedef float f32x4 __attribute__((ext_vector_type(4)));

#define SEQ 2048
#define DIM 4096
#define NH 32
#define NKV 8
#define HD 128
// 1/sqrt(128) * log2(e)  -- exp2-based softmax, scale folded into Q epilogue
#define QSCALE_LOG2E 0.12753785222167917f

__device__ inline u16 f2bf(float f) {
    unsigned int u = __float_as_uint(f);
    unsigned int r = (u + 0x7fffu + ((u >> 16) & 1u)) >> 16;
    return (u16)r;
}

__device__ inline void async16(const void* g, void* l) {
    __builtin_amdgcn_global_load_lds(
        (const __attribute__((address_space(1))) void*)g,
        (__attribute__((address_space(3))) void*)l, 16, 0, 0);
}

// ---------------- fused fp32 -> bf16 cast of all 5 tensors ----------------
__global__ __launch_bounds__(256) void cast_all(const float* __restrict__ x,
                                                const float* __restrict__ wq,
                                                const float* __restrict__ wk,
                                                const float* __restrict__ wv,
                                                const float* __restrict__ wo,
                                                u16* __restrict__ dst) {
    size_t i4 = (size_t)blockIdx.x * 256 + threadIdx.x;  // float4 group index
    size_t e = i4 * 4;                                   // element index
    const float* src;
    size_t off;  // segment start (elements)
    if (e < 8388608ull)       { src = x;  off = 0; }
    else if (e < 25165824ull) { src = wq; off = 8388608ull; }
    else if (e < 29360128ull) { src = wk; off = 25165824ull; }
    else if (e < 33554432ull) { src = wv; off = 29360128ull; }
    else                      { src = wo; off = 33554432ull; }
    float4 v = ((const float4*)src)[i4 - off / 4];
    ushort4 o;
    o.x = f2bf(v.x); o.y = f2bf(v.y); o.z = f2bf(v.z); o.w = f2bf(v.w);
    ((ushort4*)dst)[i4] = o;
}

// ======= Deep-pipelined GEMM: C[M,N] = A[M,K] * B[N,K]^T (bf16, fp32 acc) ===
// BM=128 BN=256 BK=64, 512 threads = 8 waves (2M x 4N), wave tile 64x64.
// Triple-buffered LDS (144 KB): loads for tiles t+1 and t+2 in flight while
// computing tile t; counted s_waitcnt vmcnt(12) (6 loads/thread/tile), raw
// s_barrier (no vmcnt(0) drain in the main loop).
// Reader==stager wave specialization: each LDS region is staged only by the
// waves that read it, so per-wave vmcnt + barrier proves completeness.
// LDS chunk swizzle: global chunk ch lands at slot ch^(row&7) (pre-swizzled
// global source, linear global_load_lds dest); ds_read_b128 then sees <=2-way
// bank aliasing per 16-lane phase (free).
// MODE 0: fp32 row-major out. MODE 1: QKV-routed epilogue with fused RoPE.
template <int MODE>
__global__ __launch_bounds__(512, 2) void gemm8p(const u16* __restrict__ A,
                                                 const u16* __restrict__ B,
                                                 void* __restrict__ C0,
                                                 void* __restrict__ C1,
                                                 void* __restrict__ C2,
                                                 const float* __restrict__ fc,
                                                 const float* __restrict__ fs,
                                                 int M, int N, int K) {
    extern __shared__ u16 sm[];
    u16* As = sm;                   // [3][128*64]
    u16* Bs = sm + 3 * 128 * 64;    // [3][256*64]

    const int tid = threadIdx.x;
    const int lane = tid & 63;
    const int wid = tid >> 6;
    const int wr = wid >> 2;        // 0..1  (M direction)
    const int wc = wid & 3;         // 0..3  (N direction)
    const int quad = lane >> 4;
    const int l16 = lane & 15;

    // XCD-aware bijective block swizzle (nwg % 8 == 0 for both launches)
    const int nwg = gridDim.x * gridDim.y;
    int id = blockIdx.y * gridDim.x + blockIdx.x;
    int swz = (id & 7) * (nwg >> 3) + (id >> 3);
    const int bm = (swz / gridDim.x) * 128;
    const int bn = (swz % gridDim.x) * 256;

    f32x4 acc[4][4] = {};

    // ---- stage K-tile t into buffer sb (6 x global_load_lds 16B per thread:
    //      2 for the A quarter this wave reads, 4 for the B slice it reads) ----
    auto stage = [&](int sb, int t) {
        const int k0 = t << 6;
        {   // A rows [wr*64, wr*64+64): staged by the 4 waves with this wr
            int s0 = wc * 64 + lane;            // 0..255
#pragma unroll
            for (int r = 0; r < 2; ++r) {
                int S = r * 256 + s0;           // 0..511 = row*8 + slot
                int row = S >> 3, sl = S & 7;
                int ch = sl ^ (row & 7);
                const u16* g = &A[(size_t)(bm + wr * 64 + row) * K + k0 + ch * 8];
                async16(g, (void*)&As[sb * (128 * 64) + wr * (64 * 64) + S * 8]);
            }
        }
        {   // B rows [wc*64, wc*64+64): staged by the 2 waves with this wc
            int s0 = wr * 64 + lane;            // 0..127
#pragma unroll
            for (int r = 0; r < 4; ++r) {
                int S = r * 128 + s0;           // 0..511
                int row = S >> 3, sl = S & 7;
                int ch = sl ^ (row & 7);
                const u16* g = &B[(size_t)(bn + wc * 64 + row) * K + k0 + ch * 8];
                async16(g, (void*)&Bs[sb * (256 * 64) + wc * (64 * 64) + S * 8]);
            }
        }
    };

    // ---- compute one K-tile from buffer p: 2 ks phases x 16 MFMA ----
    const int chsw = l16 & 7;   // (row & 7) == (l16 & 7) for all frag rows
    auto compute = [&](int p) {
        const u16* as = As + p * (128 * 64) + wr * (64 * 64);
        const u16* bs = Bs + p * (256 * 64) + wc * (64 * 64);
#pragma unroll
        for (int ks = 0; ks < 2; ++ks) {
            const int slot = ((ks * 4 + quad) ^ chsw) * 8;
            bf16_8 a[4], b[4];
#pragma unroll
            for (int i = 0; i < 4; ++i)
                a[i] = *(const bf16_8*)&as[(i * 16 + l16) * 64 + slot];
#pragma unroll
            for (int j = 0; j < 4; ++j)
                b[j] = *(const bf16_8*)&bs[(j * 16 + l16) * 64 + slot];
            __builtin_amdgcn_s_setprio(1);
#pragma unroll
            for (int i = 0; i < 4; ++i)
#pragma unroll
                for (int j = 0; j < 4; ++j)
                    acc[i][j] = __builtin_amdgcn_mfma_f32_16x16x32_bf16(a[i], b[j], acc[i][j], 0, 0, 0);
            __builtin_amdgcn_s_setprio(0);
        }
    };

    const int NT = K >> 6;   // 64 for K=4096
    stage(0, 0);
    stage(1, 1);             // 12 loads/thread outstanding

    int p = 0;
    for (int t = 0; t < NT - 2; ++t) {
        int sb = p + 2; if (sb >= 3) sb -= 3;
        stage(sb, t + 2);                                   // -> 18 outstanding
        asm volatile("s_waitcnt vmcnt(12)" ::: "memory");   // tile t landed
        __builtin_amdgcn_s_barrier();
        compute(p);
        __builtin_amdgcn_s_barrier();                       // reads done before re-stage
        p = (p == 2) ? 0 : p + 1;
    }
    asm volatile("s_waitcnt vmcnt(6)" ::: "memory");        // tile NT-2 landed
    __builtin_amdgcn_s_barrier();
    compute(p);
    __builtin_amdgcn_s_barrier();
    p = (p == 2) ? 0 : p + 1;
    asm volatile("s_waitcnt vmcnt(0)" ::: "memory");        // tile NT-1 landed
    __builtin_amdgcn_s_barrier();
    compute(p);

    const int wm = wr * 64;
    const int wn = wc * 64;

    if (MODE == 0) {
        float* Cf = (float*)C0;
#pragma unroll
        for (int i = 0; i < 4; ++i)
#pragma unroll
            for (int j = 0; j < 4; ++j)
#pragma unroll
                for (int r = 0; r < 4; ++r)
                    Cf[(size_t)(bm + wm + i * 16 + quad * 4 + r) * N + (bn + wn + j * 16 + l16)] =
                        acc[i][j][r];
    } else {
        // QKV routing; bn is a multiple of 256 so the whole block takes one branch
        u16* Qb = (u16*)C0;
        u16* Kb = (u16*)C1;
        u16* Vt = (u16*)C2;
        if (bn < 5120) {
            const bool isQ = bn < 4096;
            const float osc = isQ ? QSCALE_LOG2E : 1.0f;
#pragma unroll
            for (int i = 0; i < 4; ++i)
#pragma unroll
                for (int j = 0; j < 4; ++j) {
                    int n = bn + wn + j * 16 + l16;
                    int pp = (n & 127) >> 1;
                    bool odd = (l16 & 1);
#pragma unroll
                    for (int r = 0; r < 4; ++r) {
                        int m = bm + wm + i * 16 + quad * 4 + r;
                        float v = acc[i][j][r];
                        float u = __shfl_xor(v, 1);
                        float c = fc[m * 64 + pp];
                        float s = fs[m * 64 + pp];
                        float o = (odd ? (u * s + v * c) : (v * c - u * s)) * osc;
                        if (isQ)
                            Qb[(size_t)m * 4096 + n] = f2bf(o);
                        else
                            Kb[(size_t)m * 1024 + (n - 4096)] = f2bf(o);
                    }
                }
        } else {
            // V range: store transposed (d-major), no rope
#pragma unroll
            for (int i = 0; i < 4; ++i)
#pragma unroll
                for (int j = 0; j < 4; ++j) {
                    int n = bn + wn + j * 16 + l16;
                    ushort4 o;
                    o.x = f2bf(acc[i][j][0]);
                    o.y = f2bf(acc[i][j][1]);
                    o.z = f2bf(acc[i][j][2]);
                    o.w = f2bf(acc[i][j][3]);
                    *(ushort4*)&Vt[(size_t)(n - 5120) * SEQ + (bm + wm + i * 16 + quad * 4)] = o;
                }
        }
    }
}

// ---------------- Flash attention, S^T formulation (unchanged) ----------------
__global__ __launch_bounds__(256, 4) void attn_k(const u16* __restrict__ Q,
                                                 const u16* __restrict__ Kb,
                                                 const u16* __restrict__ Vt,
                                                 u16* __restrict__ Y) {
    __shared__ u16 Ks[64 * 128];   // swizzled: 16B chunks, slot = c ^ (row&15)
    __shared__ u16 Vs[128 * 64];   // swizzled: 16B chunks, slot = c ^ (row&7)
    __shared__ u16 Ps[4 * 16 * 64];// per-wave 2 KB; 8B chunks, c' = c ^ ((l16&7)<<1)
    const int tid = threadIdx.x;
    const int lane = tid & 63;
    const int w = tid >> 6;
    const int quad = lane >> 4;
    const int l16 = lane & 15;
    const int id = blockIdx.x;
    const int qt = 31 - (id >> 5);   // LPT: longest blocks first
    const int h = id & 31;
    const int kvh = h >> 2;
    const size_t qrow0 = (size_t)qt * 64;

    bf16_8 qf[4];
#pragma unroll
    for (int ks = 0; ks < 4; ++ks)
        qf[ks] = *(const bf16_8*)&Q[(qrow0 + w * 16 + l16) * DIM + h * HD + ks * 32 + quad * 8];

    f32x4 po[8] = {};    // 16 x 128 unnormalized output accumulator
    float lsum = 0.f;    // per-lane partial row sum for q-row l16

    char* psbase = (char*)Ps + w * 2048 + l16 * 128;  // this lane's P row
    const int sw = (l16 & 7) << 1;                    // 8B-chunk swizzle

    for (int kt = 0; kt <= qt; ++kt) {
#pragma unroll
        for (int r = 0; r < 4; ++r) {
            int S = r * 256 + tid;  // 0..1023
            {
                int row = S >> 4, slot = S & 15;
                int chunk = slot ^ (row & 15);
                const char* g = (const char*)Kb +
                    (((size_t)kt * 64 + row) * 1024 + kvh * HD + chunk * 8) * 2;
                async16(g, (char*)Ks + S * 16);
            }
            {
                int row = S >> 3, slot = S & 7;
                int chunk = slot ^ (row & 7);
                const char* g = (const char*)Vt +
                    (((size_t)(kvh * HD + row)) * SEQ + kt * 64 + chunk * 8) * 2;
                async16(g, (char*)Vs + S * 16);
            }
        }
        __syncthreads();

        f32x4 sc[4] = {};
#pragma unroll
        for (int ks = 0; ks < 4; ++ks)
#pragma unroll
            for (int jb = 0; jb < 4; ++jb) {
                bf16_8 kb = *(const bf16_8*)&Ks[(jb * 16 + l16) * 128 + ((ks * 4 + quad) ^ l16) * 8];
                sc[jb] = __builtin_amdgcn_mfma_f32_16x16x32_bf16(kb, qf[ks], sc[jb], 0, 0, 0);
            }

        float pv[4][4];
#pragma unroll
        for (int jb = 0; jb < 4; ++jb)
#pragma unroll
            for (int r = 0; r < 4; ++r)
                pv[jb][r] = exp2f(sc[jb][r]);

        if (kt == qt) {  // wave-uniform: mask k > q on the diagonal tile
            int qloc = w * 16 + l16;
#pragma unroll
            for (int jb = 0; jb < 4; ++jb)
#pragma unroll
                for (int r = 0; r < 4; ++r)
                    if (jb * 16 + quad * 4 + r > qloc) pv[jb][r] = 0.f;
        }

#pragma unroll
        for (int jb = 0; jb < 4; ++jb) {
            lsum += (pv[jb][0] + pv[jb][1]) + (pv[jb][2] + pv[jb][3]);
            ushort4 pk;
            pk.x = f2bf(pv[jb][0]);
            pk.y = f2bf(pv[jb][1]);
            pk.z = f2bf(pv[jb][2]);
            pk.w = f2bf(pv[jb][3]);
            int c = jb * 4 + quad;
            *(ushort4*)(psbase + ((c ^ sw) << 3)) = pk;
        }

#pragma unroll
        for (int ks = 0; ks < 2; ++ks) {
            int c = ks * 8 + quad * 2;
            bf16_8 pf = *(const bf16_8*)(psbase + ((c ^ sw) << 3));
#pragma unroll
            for (int n = 0; n < 8; ++n) {
                bf16_8 vf = *(const bf16_8*)&Vs[(n * 16 + l16) * 64 + (((ks * 4 + quad) ^ (l16 & 7))) * 8];
                po[n] = __builtin_amdgcn_mfma_f32_16x16x32_bf16(pf, vf, po[n], 0, 0, 0);
            }
        }
        __syncthreads();
    }

    lsum += __shfl_xor(lsum, 16);
    lsum += __shfl_xor(lsum, 32);
    float inv = 1.f / lsum;
#pragma unroll
    for (int r = 0; r < 4; ++r) {
        float invr = __shfl(inv, quad * 4 + r);
        size_t row = qrow0 + w * 16 + quad * 4 + r;
#pragma unroll
        for (int n = 0; n < 8; ++n)
            Y[row * DIM + h * HD + n * 16 + l16] = f2bf(po[n][r] * invr);
    }
}

extern "C" void kernel_launch(void* const* d_in, const int* in_sizes, int n_in,
                              void* d_out, int out_size, void* d_ws, size_t ws_size,
                              hipStream_t stream) {
    const float* x  = (const float*)d_in[0];
    const float* wq = (const float*)d_in[1];
    const float* wk = (const float*)d_in[2];
    const float* wv = (const float*)d_in[3];
    const float* wo = (const float*)d_in[4];
    const float* fc = (const float*)d_in[5];
    const float* fs = (const float*)d_in[6];

    char* ws = (char*)d_ws;
    const size_t MB = 1u << 20;
    u16* xb    = (u16*)(ws);             // 2048x4096 bf16       (16 MB)
    u16* wqkvb = (u16*)(ws + 16 * MB);   // 6144x4096 (wq|wk|wv) (48 MB)
    u16* wob   = (u16*)(ws + 64 * MB);   // 4096x4096            (32 MB)
    u16* Qb    = (u16*)(ws + 96 * MB);   // 2048x4096            (16 MB)
    u16* Kb    = (u16*)(ws + 112 * MB);  // 2048x1024            (4 MB)
    u16* Vtb   = (u16*)(ws + 116 * MB);  // 1024x2048 (V^T)      (4 MB)
    u16* Yb    = (u16*)(ws + 120 * MB);  // 2048x4096            (16 MB)

    const int smbytes = 3 * (128 * 64 + 256 * 64) * 2;  // 147456 B
    static int inited = 0;
    if (!inited) {
        hipFuncSetAttribute(reinterpret_cast<const void*>(&gemm8p<1>),
                            hipFuncAttributeMaxDynamicSharedMemorySize, smbytes);
        hipFuncSetAttribute(reinterpret_cast<const void*>(&gemm8p<0>),
                            hipFuncAttributeMaxDynamicSharedMemorySize, smbytes);
        inited = 1;
    }

    // single fused cast: [x | wq | wk | wv | wo] -> bf16 at ws[0..96MB)
    cast_all<<<49152, 256, 0, stream>>>(x, wq, wk, wv, wo, (u16*)ws);

    // fused QKV projection + RoPE (+ Q pre-scale incl. log2e) epilogue
    gemm8p<1><<<dim3(24, 16), 512, smbytes, stream>>>(xb, wqkvb, Qb, Kb, Vtb, fc, fs,
                                                      2048, 6144, 4096);

    // attention (LPT-ordered 1D grid)
    attn_k<<<dim3(1024), 256, 0, stream>>>(Qb, Kb, Vtb, Yb);

    // output projection -> fp32 d_out
    gemm8p<0><<<dim3(16, 16), 512, smbytes, stream>>>(Yb, wob, (float*)d_out, nullptr, nullptr,
                                                      nullptr, nullptr, 2048, 4096, 4096);
}